// Round 20
// baseline (352.345 us; speedup 1.0000x reference)
//
#include <hip/hip_runtime.h>
#include <cstdint>
#include <cstddef>

// ---------------- types ----------------
typedef short short4v __attribute__((ext_vector_type(4)));
typedef short short8v __attribute__((ext_vector_type(8)));
typedef float f32x4   __attribute__((ext_vector_type(4)));

#define T_LEN  2048
#define HDIM   4096
#define NHEADS 32
#define HEADD  128
#define QKVN   4608   // (32 + 2*2) * 128

static __device__ __forceinline__ short f2bf(float f) {
  __bf16 h = (__bf16)f;               // RNE fptrunc
  return __builtin_bit_cast(short, h);
}
static __device__ __forceinline__ float bf2f(short u) {
  return __builtin_bit_cast(float, ((unsigned int)(unsigned short)u) << 16);  // exact
}

static __device__ __forceinline__ void gload_lds16(const void* g, void* l) {
  // async global->LDS, 16B per lane; LDS dest is wave-uniform base + lane*16
  __builtin_amdgcn_global_load_lds((const __attribute__((address_space(1))) void*)g,
                                   (__attribute__((address_space(3))) void*)l,
                                   16, 0, 0);
}

// ---------------- casts ----------------
__global__ void cast_pair(const float* __restrict__ a, short* __restrict__ oa, int na4,
                          const float* __restrict__ b, short* __restrict__ ob, int nb4) {
  int idx = blockIdx.x * blockDim.x + threadIdx.x;
  int stride = gridDim.x * blockDim.x;
  const int ntot = na4 + nb4;
  for (int i = idx; i < ntot; i += stride) {
    const float4* src = (i < na4) ? ((const float4*)a + i) : ((const float4*)b + (i - na4));
    short4v* dst      = (i < na4) ? ((short4v*)oa + i)     : ((short4v*)ob + (i - na4));
    float4 v = *src;
    short4v o;
    o[0] = f2bf(v.x); o[1] = f2bf(v.y); o[2] = f2bf(v.z); o[3] = f2bf(v.w);
    *dst = o;
  }
}

__global__ void cast_f32_to_bf16(const float* __restrict__ in, short* __restrict__ out, int n4) {
  int idx = blockIdx.x * blockDim.x + threadIdx.x;
  int stride = gridDim.x * blockDim.x;
  const float4* in4 = (const float4*)in;
  short4v* out4 = (short4v*)out;
  for (int i = idx; i < n4; i += stride) {
    float4 v = in4[i];
    short4v o;
    o[0] = f2bf(v.x); o[1] = f2bf(v.y); o[2] = f2bf(v.z); o[3] = f2bf(v.w);
    out4[i] = o;
  }
}

// ---------------- GEMM  C[M][N] = A[M][K] * B[N][K]^T (+bias) ---------------
// R19-measured (97us): BK=64 single-buffer (32KB, 2 blocks/CU), rule-#21 XOR
// swizzle, T1 bijective XCD swizzle.
template <int OUT_BF16>
__global__ __launch_bounds__(256, 2) void gemm_bt(
    const short* __restrict__ A,     // [M][K] bf16
    const short* __restrict__ B,     // [N][K] bf16
    const float* __restrict__ bias,  // [N] f32 or nullptr
    void* __restrict__ Cout,         // [M][N] f32 or bf16
    int M, int N, int K)
{
  __shared__ short sA[128 * 64];   // [row][k] 128B rows, swizzled, 16KB
  __shared__ short sB[128 * 64];
  const int tid  = threadIdx.x;
  const int lane = tid & 63;
  const int wv   = tid >> 6;
  const int wr   = wv >> 1;
  const int wc   = wv & 1;

  const int nwg  = gridDim.x * gridDim.y;
  int wgid = blockIdx.y * gridDim.x + blockIdx.x;
  wgid = (wgid & 7) * (nwg >> 3) + (wgid >> 3);
  const int bn0 = (wgid / gridDim.y) * 128;
  const int bm0 = (wgid % gridDim.y) * 128;

  const int fr  = lane & 15;
  const int fkb = (lane >> 4) << 4;
  const int swz = (fr & 7) << 4;

  const int c_row  = tid >> 3;
  const int c_colb = (tid & 7) << 4;
  const int c_scol = (c_colb ^ ((c_row & 7) << 4)) >> 1;

  auto STAGE = [&](int kt) {
#pragma unroll
    for (int i = 0; i < 4; i++) {
      const int row = i * 32 + c_row;
      gload_lds16(A + (size_t)(bm0 + row) * K + kt + c_scol,
                  (char*)sA + (size_t)(i * 256 + wv * 64) * 16);
      gload_lds16(B + (size_t)(bn0 + row) * K + kt + c_scol,
                  (char*)sB + (size_t)(i * 256 + wv * 64) * 16);
    }
  };

  f32x4 zero = {0.f, 0.f, 0.f, 0.f};
  f32x4 acc[4][4];
#pragma unroll
  for (int m = 0; m < 4; m++)
#pragma unroll
    for (int n = 0; n < 4; n++) acc[m][n] = zero;

  for (int kt = 0; kt < K; kt += 64) {
    STAGE(kt);
    __syncthreads();
    const char* aB = (const char*)sA;
    const char* bB = (const char*)sB;
#pragma unroll
    for (int ks = 0; ks < 2; ks++) {
      short8v af[4], bfr[4];
#pragma unroll
      for (int m = 0; m < 4; m++) {
        const int row = wr * 64 + m * 16 + fr;
        af[m] = *(const short8v*)(aB + row * 128 + ((ks * 64 + fkb) ^ swz));
      }
#pragma unroll
      for (int n = 0; n < 4; n++) {
        const int row = wc * 64 + n * 16 + fr;
        bfr[n] = *(const short8v*)(bB + row * 128 + ((ks * 64 + fkb) ^ swz));
      }
#pragma unroll
      for (int m = 0; m < 4; m++)
#pragma unroll
        for (int n = 0; n < 4; n++)
          acc[m][n] = __builtin_amdgcn_mfma_f32_16x16x32_bf16(af[m], bfr[n], acc[m][n], 0, 0, 0);
    }
    __syncthreads();
  }

  const int rg = (lane >> 4) * 4;
#pragma unroll
  for (int m = 0; m < 4; m++) {
#pragma unroll
    for (int n = 0; n < 4; n++) {
      const int gcol = bn0 + wc * 64 + n * 16 + fr;
      const float bv = bias ? bias[gcol] : 0.0f;
#pragma unroll
      for (int j = 0; j < 4; j++) {
        const int grow = bm0 + wr * 64 + m * 16 + rg + j;
        const float v = acc[m][n][j] + bv;
        if (OUT_BF16)
          ((short*)Cout)[(size_t)grow * N + gcol] = f2bf(v);
        else
          ((float*)Cout)[(size_t)grow * N + gcol] = v;
      }
    }
  }
}

// ---------------- per-head RMSNorm + RoPE, 4 heads per 256-thread block -----
__global__ __launch_bounds__(256) void qkv_post_kernel(
    const short* __restrict__ qkvb,      // [T][4608] bf16 (bias included)
    const int*   __restrict__ positions,
    const float* __restrict__ q_ln,      // [128] f32
    const float* __restrict__ k_ln,      // [128] f32
    short* __restrict__ Qb,   // [NH][T][HD]
    short* __restrict__ Kb,   // [NKV][T][HD]
    short* __restrict__ Vt)   // [NKV][HD][T]
{
  const int t = blockIdx.x;
  const int h = blockIdx.y * 4 + (threadIdx.x >> 6);
  const int lane = threadIdx.x & 63;
  const unsigned int pk =
      ((const unsigned int*)(qkvb + (size_t)t * QKVN + h * HEADD))[lane];
  float x = bf2f((short)(pk & 0xffffu));
  float y = bf2f((short)(pk >> 16));

  if (h >= 34) { // V: transpose only
    const int hv = h - 34;
    short* dst = Vt + ((size_t)hv * HEADD + 2 * lane) * T_LEN + t;
    dst[0]     = f2bf(x);
    dst[T_LEN] = f2bf(y);
    return;
  }

  float ss = x * x + y * y;
#pragma unroll
  for (int d = 32; d > 0; d >>= 1) ss += __shfl_xor(ss, d);
  const float r = rsqrtf(ss * (1.0f / 128.0f) + 1e-5f);
  const float* lnw = (h < 32) ? q_ln : k_ln;
  x = x * r * lnw[2 * lane];
  y = y * r * lnw[2 * lane + 1];

  if (lane < 32) { // rotary pairs (2i,2i+1), i<32: ang = pos * 10000^(-i/32)
    const float pos = (float)positions[t];
    const float ang = pos * powf(10000.0f, -(float)lane * (1.0f / 32.0f));
    const float c = cosf(ang), s = sinf(ang);
    const float r1 = x * c - y * s;
    const float r2 = y * c + x * s;
    x = r1; y = r2;
  }

  short* dst = (h < 32) ? (Qb + ((size_t)h * T_LEN + t) * HEADD + 2 * lane)
                        : (Kb + ((size_t)(h - 32) * T_LEN + t) * HEADD + 2 * lane);
  dst[0] = f2bf(x);
  dst[1] = f2bf(y);
}

// ---------------- causal flash attention, GQA 16:1 ----------------
// KVBLK=128 SINGLE-buffer (Ks 32KB + Vs 32KB + pbuf 16KB = 80KB, 2 blk/CU):
// halves vmcnt-drain events per KV row vs KVBLK=64 dbuf at the same LDS —
// the R19 gemm lever applied to attn. P processed in two 64-col halves so
// pbuf stays 16KB; PV accumulation order over s unchanged.
__global__ __launch_bounds__(256, 2) void attn_kernel(
    const short* __restrict__ Qb,   // [NH][T][HD]
    const short* __restrict__ Kb,   // [NKV][T][HD]
    const short* __restrict__ Vt,   // [NKV][HD][T]
    short* __restrict__ attn_out)   // [T][NH*HD] bf16
{
  __shared__ short Ks[128 * 128];     // [s][d] swizzled 256B rows, 32KB
  __shared__ short Vs[128 * 128];     // [d][s] swizzled 256B rows, 32KB
  __shared__ short pbuf[4][32 * 64];  // per-wave P half-tile, 128B rows, 16KB
  const int blk  = gridDim.x - 1 - blockIdx.x;   // longest blocks first
  const int h    = blockIdx.y;
  const int hkv  = h >> 4;
  const int tid  = threadIdx.x;
  const int lane = tid & 63;
  const int wv   = tid >> 6;
  const int B0   = blk * 128;
  const int qrow0 = B0 + wv * 32;
  const int fr = lane & 15;
  const int fk = (lane >> 4) * 8;     // shorts
  const int fkb = (lane >> 4) << 4;   // bytes
  const int rg = (lane >> 4) * 4;
  const int swz = (fr & 7) << 4;

  const short* Kh = Kb + (size_t)hkv * T_LEN * HEADD;
  const short* Vh = Vt + (size_t)hkv * HEADD * T_LEN;

  short8v qf[2][4];
#pragma unroll
  for (int g = 0; g < 2; g++) {
    const short* Qrow = Qb + ((size_t)h * T_LEN + qrow0 + g * 16 + fr) * HEADD + fk;
#pragma unroll
    for (int d0 = 0; d0 < 4; d0++) qf[g][d0] = *(const short8v*)(Qrow + d0 * 32);
  }

  float mrow[2][4], lrow[2][4];
#pragma unroll
  for (int g = 0; g < 2; g++)
#pragma unroll
    for (int j = 0; j < 4; j++) { mrow[g][j] = -1e30f; lrow[g][j] = 0.f; }
  f32x4 zero = {0.f, 0.f, 0.f, 0.f};
  f32x4 o[2][8];
#pragma unroll
  for (int g = 0; g < 2; g++)
#pragma unroll
    for (int d = 0; d < 8; d++) o[g][d] = zero;

  char* pb = (char*)&pbuf[wv][0];
  const float scale = 0.08838834764831845f; // 128^-0.5
  const int nt = blk + 1;                   // KV tiles of 128

  // stage tile t (128 KV rows): 8 issues K + 8 issues V, 256B rows, rule-#21
  auto STAGE = [&](int t) {
    const int s0 = t * 128;
#pragma unroll
    for (int i = 0; i < 8; i++) {          // K: [row s 0..127][col d], 256B rows
      const int c    = i * 256 + tid;
      const int row  = c >> 4;
      const int colb = (c & 15) << 4;
      const int scol = (colb ^ ((row & 7) << 4)) >> 1;
      gload_lds16(Kh + (size_t)(s0 + row) * HEADD + scol,
                  (char*)Ks + (size_t)(i * 256 + wv * 64) * 16);
    }
#pragma unroll
    for (int i = 0; i < 8; i++) {          // V: [row d 0..127][col s], 256B rows
      const int c    = i * 256 + tid;
      const int row  = c >> 4;
      const int colb = (c & 15) << 4;
      const int scol = (colb ^ ((row & 7) << 4)) >> 1;
      gload_lds16(Vh + (size_t)row * T_LEN + s0 + scol,
                  (char*)Vs + (size_t)(i * 256 + wv * 64) * 16);
    }
  };

  for (int t = 0; t < nt; ++t) {
    STAGE(t);
    __syncthreads();   // single vmcnt drain per 128 KV rows
    const int s0 = t * 128;
    const char* KsB = (const char*)Ks;
    const char* VsB = (const char*)Vs;

    // ---- scores: 8 sub-tiles of 16 KV rows (swizzled ds_read_b128)
    float scv[2][8][4];
#pragma unroll
    for (int sub = 0; sub < 8; sub++) {
      const char* Kbase = KsB + (sub * 16 + fr) * 256;
      f32x4 a0 = zero, a1 = zero;
#pragma unroll
      for (int d0 = 0; d0 < 4; d0++) {
        short8v kf = *(const short8v*)(Kbase + ((d0 * 64 + fkb) ^ swz));
        a0 = __builtin_amdgcn_mfma_f32_16x16x32_bf16(qf[0][d0], kf, a0, 0, 0, 0);
        a1 = __builtin_amdgcn_mfma_f32_16x16x32_bf16(qf[1][d0], kf, a1, 0, 0, 0);
      }
#pragma unroll
      for (int j = 0; j < 4; j++) {
        scv[0][sub][j] = a0[j] * scale;
        scv[1][sub][j] = a1[j] * scale;
      }
    }
    // ---- causal mask: only the last tile touches the diagonal
    if (t == nt - 1) {
#pragma unroll
      for (int g = 0; g < 2; g++)
#pragma unroll
        for (int sub = 0; sub < 8; sub++) {
          const int colp = s0 + sub * 16 + fr;
#pragma unroll
          for (int j = 0; j < 4; j++)
            if (colp > qrow0 + g * 16 + rg + j) scv[g][sub][j] = -1e30f;
        }
    }
    // ---- defer-max gate (T13, THR=8)
    float pmax[2][4];
#pragma unroll
    for (int g = 0; g < 2; g++)
#pragma unroll
      for (int j = 0; j < 4; j++) {
        float m0 = fmaxf(fmaxf(scv[g][0][j], scv[g][1][j]),
                         fmaxf(scv[g][2][j], scv[g][3][j]));
        float m1 = fmaxf(fmaxf(scv[g][4][j], scv[g][5][j]),
                         fmaxf(scv[g][6][j], scv[g][7][j]));
        pmax[g][j] = fmaxf(m0, m1);
      }
    float growth = -1e30f;
#pragma unroll
    for (int g = 0; g < 2; g++)
#pragma unroll
      for (int j = 0; j < 4; j++) growth = fmaxf(growth, pmax[g][j] - mrow[g][j]);
    if (!__all(growth <= 8.0f)) {
#pragma unroll
      for (int g = 0; g < 2; g++)
#pragma unroll
        for (int j = 0; j < 4; j++) {
          float mx = pmax[g][j];
#pragma unroll
          for (int d = 1; d < 16; d <<= 1) mx = fmaxf(mx, __shfl_xor(mx, d));
          const float mn = fmaxf(mrow[g][j], mx);
          const float c  = __expf(mrow[g][j] - mn);
          mrow[g][j] = mn;
          lrow[g][j] *= c;
#pragma unroll
          for (int df = 0; df < 8; df++) o[g][df][j] *= c;
        }
    }
    // ---- two 64-col halves: exp + P->LDS, then PV (pbuf reused per half)
#pragma unroll
    for (int half = 0; half < 2; half++) {
#pragma unroll
      for (int g = 0; g < 2; g++)
#pragma unroll
        for (int j = 0; j < 4; j++) {
          const int prow = g * 16 + rg + j;
          char* prb = pb + prow * 128;
          const int rswz = ((rg + j) & 7) << 4;
          float ps = 0.f;
#pragma unroll
          for (int s4 = 0; s4 < 4; s4++) {
            const float p = __expf(scv[g][half * 4 + s4][j] - mrow[g][j]);
            ps += p;
            *(short*)(prb + ((((s4 * 16 + fr) << 1)) ^ rswz)) = f2bf(p);
          }
          lrow[g][j] += ps;
        }
      asm volatile("" ::: "memory");  // order LDS writes before A-frag reads
      short8v pf[2][2];
#pragma unroll
      for (int g = 0; g < 2; g++)
#pragma unroll
        for (int ks = 0; ks < 2; ks++)
          pf[g][ks] = *(const short8v*)(pb + (g * 16 + fr) * 128 + ((ks * 64 + fkb) ^ swz));
#pragma unroll
      for (int df = 0; df < 8; df++) {
        const char* Vbase = VsB + (df * 16 + fr) * 256;
        short8v vf0 = *(const short8v*)(Vbase + ((half * 128 + 0 + fkb) ^ swz));
        short8v vf1 = *(const short8v*)(Vbase + ((half * 128 + 64 + fkb) ^ swz));
        o[0][df] = __builtin_amdgcn_mfma_f32_16x16x32_bf16(pf[0][0], vf0, o[0][df], 0, 0, 0);
        o[0][df] = __builtin_amdgcn_mfma_f32_16x16x32_bf16(pf[0][1], vf1, o[0][df], 0, 0, 0);
        o[1][df] = __builtin_amdgcn_mfma_f32_16x16x32_bf16(pf[1][0], vf0, o[1][df], 0, 0, 0);
        o[1][df] = __builtin_amdgcn_mfma_f32_16x16x32_bf16(pf[1][1], vf1, o[1][df], 0, 0, 0);
      }
      asm volatile("" ::: "memory");  // PV reads done before next half's writes
    }
    __syncthreads();   // all waves done reading Ks/Vs before next STAGE
  }

  // ---- final denominator reduce + output
#pragma unroll
  for (int g = 0; g < 2; g++)
#pragma unroll
    for (int j = 0; j < 4; j++) {
#pragma unroll
      for (int d = 1; d < 16; d <<= 1) lrow[g][j] += __shfl_xor(lrow[g][j], d);
    }
#pragma unroll
  for (int g = 0; g < 2; g++)
#pragma unroll
    for (int df = 0; df < 8; df++)
#pragma unroll
      for (int j = 0; j < 4; j++) {
        const float v = o[g][df][j] / lrow[g][j];
        attn_out[(size_t)(qrow0 + g * 16 + rg + j) * HDIM + h * HEADD + df * 16 + fr] = f2bf(v);
      }
}

// ---------------- launch ----------------
extern "C" void kernel_launch(void* const* d_in, const int* in_sizes, int n_in,
                              void* d_out, int out_size, void* d_ws, size_t ws_size,
                              hipStream_t stream) {
  (void)out_size; (void)ws_size;
  // size-based input remap (robust to any d_in permutation; sizes are unique)
  int ip = 0, ih = 1, iwq = 2, ib = 3, iwd = 4, il0 = 5, il1 = 6;
  if (n_in == 7) {
    int p = -1, hh = -1, wq = -1, b = -1, wd = -1, l0 = -1, l1 = -1, ok = 1;
    for (int i = 0; i < 7; i++) {
      switch (in_sizes[i]) {
        case 2048:     p  = i; break;
        case 8388608:  hh = i; break;
        case 18874368: wq = i; break;
        case 4608:     b  = i; break;
        case 16777216: wd = i; break;
        case 128:      if (l0 < 0) l0 = i; else l1 = i; break;
        default:       ok = 0; break;
      }
    }
    if (ok && p >= 0 && hh >= 0 && wq >= 0 && b >= 0 && wd >= 0 && l0 >= 0 && l1 >= 0) {
      ip = p; ih = hh; iwq = wq; ib = b; iwd = wd; il0 = l0; il1 = l1;
    }
  }

  const int*   positions = (const int*)d_in[ip];
  const float* hidden    = (const float*)d_in[ih];
  const float* w_qkv     = (const float*)d_in[iwq];
  const float* b_qkv     = (const float*)d_in[ib];
  const float* w_dense   = (const float*)d_in[iwd];
  const float* q_ln      = (const float*)d_in[il0];
  const float* k_ln      = (const float*)d_in[il1];

  char* ws = (char*)d_ws;
  // lifetime-aliased workspace (peak ~73.4 MB):
  short* Ahs   = (short*)(ws + 0);                   // 16.8 MB (dead after gemm1)
  short* Qb    = (short*)(ws + 0);                   // 16.8 MB (aliases Ahs)
  short* Wqkv  = (short*)(ws + (size_t)16777216);    // 37.7 MB (dead after gemm1)
  short* Kb    = (short*)(ws + (size_t)16777216);    // 1.0 MB  (aliases Wqkv)
  short* Vt    = (short*)(ws + (size_t)17825792);    // 1.0 MB  (aliases Wqkv)
  short* Wd    = (short*)(ws + (size_t)18874368);    // 33.5 MB (aliases Wqkv)
  short* qkvb  = (short*)(ws + (size_t)54525952);    // 18.9 MB bf16 (dead after qkv_post)
  short* attnb = (short*)(ws + (size_t)54525952);    // 16.8 MB (aliases qkvb)

  cast_pair<<<dim3(3072), dim3(256), 0, stream>>>(
      hidden, Ahs, (T_LEN * HDIM) / 4, w_qkv, Wqkv, (QKVN * HDIM) / 4);
  gemm_bt<1><<<dim3(QKVN / 128, T_LEN / 128), dim3(256), 0, stream>>>(
      Ahs, Wqkv, b_qkv, (void*)qkvb, T_LEN, QKVN, HDIM);
  qkv_post_kernel<<<dim3(T_LEN, 9), dim3(256), 0, stream>>>(
      qkvb, positions, q_ln, k_ln, Qb, Kb, Vt);
  cast_f32_to_bf16<<<dim3(2048), dim3(256), 0, stream>>>(w_dense, Wd, (HDIM * HDIM) / 4);
  attn_kernel<<<dim3(16, NHEADS), dim3(256), 0, stream>>>(Qb, Kb, Vt, attnb);
  gemm_bt<0><<<dim3(HDIM / 128, T_LEN / 128), dim3(256), 0, stream>>>(
      attnb, Wd, nullptr, d_out, T_LEN, HDIM, HDIM);
}

// Round 21
// 316.169 us; speedup vs baseline: 1.1144x; 1.1144x over previous
//
#include <hip/hip_runtime.h>
#include <cstdint>
#include <cstddef>

// ---------------- types ----------------
typedef short short4v __attribute__((ext_vector_type(4)));
typedef short short8v __attribute__((ext_vector_type(8)));
typedef float f32x4   __attribute__((ext_vector_type(4)));

#define T_LEN  2048
#define HDIM   4096
#define NHEADS 32
#define HEADD  128
#define QKVN   4608   // (32 + 2*2) * 128

static __device__ __forceinline__ short f2bf(float f) {
  __bf16 h = (__bf16)f;               // RNE fptrunc
  return __builtin_bit_cast(short, h);
}
static __device__ __forceinline__ float bf2f(short u) {
  return __builtin_bit_cast(float, ((unsigned int)(unsigned short)u) << 16);  // exact
}

static __device__ __forceinline__ void gload_lds16(const void* g, void* l) {
  // async global->LDS, 16B per lane; LDS dest is wave-uniform base + lane*16
  __builtin_amdgcn_global_load_lds((const __attribute__((address_space(1))) void*)g,
                                   (__attribute__((address_space(3))) void*)l,
                                   16, 0, 0);
}

// ---------------- casts ----------------
__global__ void cast_pair(const float* __restrict__ a, short* __restrict__ oa, int na4,
                          const float* __restrict__ b, short* __restrict__ ob, int nb4) {
  int idx = blockIdx.x * blockDim.x + threadIdx.x;
  int stride = gridDim.x * blockDim.x;
  const int ntot = na4 + nb4;
  for (int i = idx; i < ntot; i += stride) {
    const float4* src = (i < na4) ? ((const float4*)a + i) : ((const float4*)b + (i - na4));
    short4v* dst      = (i < na4) ? ((short4v*)oa + i)     : ((short4v*)ob + (i - na4));
    float4 v = *src;
    short4v o;
    o[0] = f2bf(v.x); o[1] = f2bf(v.y); o[2] = f2bf(v.z); o[3] = f2bf(v.w);
    *dst = o;
  }
}

__global__ void cast_f32_to_bf16(const float* __restrict__ in, short* __restrict__ out, int n4) {
  int idx = blockIdx.x * blockDim.x + threadIdx.x;
  int stride = gridDim.x * blockDim.x;
  const float4* in4 = (const float4*)in;
  short4v* out4 = (short4v*)out;
  for (int i = idx; i < n4; i += stride) {
    float4 v = in4[i];
    short4v o;
    o[0] = f2bf(v.x); o[1] = f2bf(v.y); o[2] = f2bf(v.z); o[3] = f2bf(v.w);
    out4[i] = o;
  }
}

// ---------------- GEMM  C[M][N] = A[M][K] * B[N][K]^T (+bias) ---------------
// R19-measured (97us): BK=64 single-buffer (32KB, 2 blocks/CU), rule-#21 XOR
// swizzle (conflicts 9.4M->0), T1 bijective XCD swizzle (FETCH 112->93MB).
template <int OUT_BF16>
__global__ __launch_bounds__(256, 2) void gemm_bt(
    const short* __restrict__ A,     // [M][K] bf16
    const short* __restrict__ B,     // [N][K] bf16
    const float* __restrict__ bias,  // [N] f32 or nullptr
    void* __restrict__ Cout,         // [M][N] f32 or bf16
    int M, int N, int K)
{
  __shared__ short sA[128 * 64];   // [row][k] 128B rows, swizzled, 16KB
  __shared__ short sB[128 * 64];
  const int tid  = threadIdx.x;
  const int lane = tid & 63;
  const int wv   = tid >> 6;
  const int wr   = wv >> 1;
  const int wc   = wv & 1;

  const int nwg  = gridDim.x * gridDim.y;
  int wgid = blockIdx.y * gridDim.x + blockIdx.x;
  wgid = (wgid & 7) * (nwg >> 3) + (wgid >> 3);
  const int bn0 = (wgid / gridDim.y) * 128;
  const int bm0 = (wgid % gridDim.y) * 128;

  const int fr  = lane & 15;
  const int fkb = (lane >> 4) << 4;
  const int swz = (fr & 7) << 4;

  const int c_row  = tid >> 3;
  const int c_colb = (tid & 7) << 4;
  const int c_scol = (c_colb ^ ((c_row & 7) << 4)) >> 1;

  auto STAGE = [&](int kt) {
#pragma unroll
    for (int i = 0; i < 4; i++) {
      const int row = i * 32 + c_row;
      gload_lds16(A + (size_t)(bm0 + row) * K + kt + c_scol,
                  (char*)sA + (size_t)(i * 256 + wv * 64) * 16);
      gload_lds16(B + (size_t)(bn0 + row) * K + kt + c_scol,
                  (char*)sB + (size_t)(i * 256 + wv * 64) * 16);
    }
  };

  f32x4 zero = {0.f, 0.f, 0.f, 0.f};
  f32x4 acc[4][4];
#pragma unroll
  for (int m = 0; m < 4; m++)
#pragma unroll
    for (int n = 0; n < 4; n++) acc[m][n] = zero;

  for (int kt = 0; kt < K; kt += 64) {
    STAGE(kt);
    __syncthreads();
    const char* aB = (const char*)sA;
    const char* bB = (const char*)sB;
#pragma unroll
    for (int ks = 0; ks < 2; ks++) {
      short8v af[4], bfr[4];
#pragma unroll
      for (int m = 0; m < 4; m++) {
        const int row = wr * 64 + m * 16 + fr;
        af[m] = *(const short8v*)(aB + row * 128 + ((ks * 64 + fkb) ^ swz));
      }
#pragma unroll
      for (int n = 0; n < 4; n++) {
        const int row = wc * 64 + n * 16 + fr;
        bfr[n] = *(const short8v*)(bB + row * 128 + ((ks * 64 + fkb) ^ swz));
      }
#pragma unroll
      for (int m = 0; m < 4; m++)
#pragma unroll
        for (int n = 0; n < 4; n++)
          acc[m][n] = __builtin_amdgcn_mfma_f32_16x16x32_bf16(af[m], bfr[n], acc[m][n], 0, 0, 0);
    }
    __syncthreads();
  }

  const int rg = (lane >> 4) * 4;
#pragma unroll
  for (int m = 0; m < 4; m++) {
#pragma unroll
    for (int n = 0; n < 4; n++) {
      const int gcol = bn0 + wc * 64 + n * 16 + fr;
      const float bv = bias ? bias[gcol] : 0.0f;
#pragma unroll
      for (int j = 0; j < 4; j++) {
        const int grow = bm0 + wr * 64 + m * 16 + rg + j;
        const float v = acc[m][n][j] + bv;
        if (OUT_BF16)
          ((short*)Cout)[(size_t)grow * N + gcol] = f2bf(v);
        else
          ((float*)Cout)[(size_t)grow * N + gcol] = v;
      }
    }
  }
}

// ---------------- per-head RMSNorm + RoPE, 4 heads per 256-thread block -----
__global__ __launch_bounds__(256) void qkv_post_kernel(
    const short* __restrict__ qkvb,      // [T][4608] bf16 (bias included)
    const int*   __restrict__ positions,
    const float* __restrict__ q_ln,      // [128] f32
    const float* __restrict__ k_ln,      // [128] f32
    short* __restrict__ Qb,   // [NH][T][HD]
    short* __restrict__ Kb,   // [NKV][T][HD]
    short* __restrict__ Vt)   // [NKV][HD][T]
{
  const int t = blockIdx.x;
  const int h = blockIdx.y * 4 + (threadIdx.x >> 6);
  const int lane = threadIdx.x & 63;
  const unsigned int pk =
      ((const unsigned int*)(qkvb + (size_t)t * QKVN + h * HEADD))[lane];
  float x = bf2f((short)(pk & 0xffffu));
  float y = bf2f((short)(pk >> 16));

  if (h >= 34) { // V: transpose only
    const int hv = h - 34;
    short* dst = Vt + ((size_t)hv * HEADD + 2 * lane) * T_LEN + t;
    dst[0]     = f2bf(x);
    dst[T_LEN] = f2bf(y);
    return;
  }

  float ss = x * x + y * y;
#pragma unroll
  for (int d = 32; d > 0; d >>= 1) ss += __shfl_xor(ss, d);
  const float r = rsqrtf(ss * (1.0f / 128.0f) + 1e-5f);
  const float* lnw = (h < 32) ? q_ln : k_ln;
  x = x * r * lnw[2 * lane];
  y = y * r * lnw[2 * lane + 1];

  if (lane < 32) { // rotary pairs (2i,2i+1), i<32: ang = pos * 10000^(-i/32)
    const float pos = (float)positions[t];
    const float ang = pos * powf(10000.0f, -(float)lane * (1.0f / 32.0f));
    const float c = cosf(ang), s = sinf(ang);
    const float r1 = x * c - y * s;
    const float r2 = y * c + x * s;
    x = r1; y = r2;
  }

  short* dst = (h < 32) ? (Qb + ((size_t)h * T_LEN + t) * HEADD + 2 * lane)
                        : (Kb + ((size_t)(h - 32) * T_LEN + t) * HEADD + 2 * lane);
  dst[0] = f2bf(x);
  dst[1] = f2bf(y);
}

// ---------------- causal flash attention, GQA 16:1 ----------------
// R19-measured structure (96.7us): KVBLK=64 DOUBLE-buffered with prefetch-
// before-compute (steady-state staging latency hidden under compute — the
// R20 lesson: never trade an existing overlap for fewer drains).
__global__ __launch_bounds__(256, 2) void attn_kernel(
    const short* __restrict__ Qb,   // [NH][T][HD]
    const short* __restrict__ Kb,   // [NKV][T][HD]
    const short* __restrict__ Vt,   // [NKV][HD][T]
    short* __restrict__ attn_out)   // [T][NH*HD] bf16
{
  __shared__ short Ks[2][64 * 128];   // [s][d] swizzled, 2x16KB
  __shared__ short Vs[2][128 * 64];   // [d][s] swizzled, 2x16KB
  __shared__ short pbuf[4][32 * 64];  // per-wave P tile [row][col] swizzled, 16KB
  const int blk  = gridDim.x - 1 - blockIdx.x;   // longest blocks first
  const int h    = blockIdx.y;
  const int hkv  = h >> 4;
  const int tid  = threadIdx.x;
  const int lane = tid & 63;
  const int wv   = tid >> 6;
  const int B0   = blk * 128;
  const int qrow0 = B0 + wv * 32;
  const int fr = lane & 15;
  const int fk = (lane >> 4) * 8;     // shorts
  const int fkb = (lane >> 4) << 4;   // bytes
  const int rg = (lane >> 4) * 4;
  const int swz = (fr & 7) << 4;

  const short* Kh = Kb + (size_t)hkv * T_LEN * HEADD;
  const short* Vh = Vt + (size_t)hkv * HEADD * T_LEN;

  short8v qf[2][4];
#pragma unroll
  for (int g = 0; g < 2; g++) {
    const short* Qrow = Qb + ((size_t)h * T_LEN + qrow0 + g * 16 + fr) * HEADD + fk;
#pragma unroll
    for (int d0 = 0; d0 < 4; d0++) qf[g][d0] = *(const short8v*)(Qrow + d0 * 32);
  }

  float mrow[2][4], lrow[2][4];
#pragma unroll
  for (int g = 0; g < 2; g++)
#pragma unroll
    for (int j = 0; j < 4; j++) { mrow[g][j] = -1e30f; lrow[g][j] = 0.f; }
  f32x4 zero = {0.f, 0.f, 0.f, 0.f};
  f32x4 o[2][8];
#pragma unroll
  for (int g = 0; g < 2; g++)
#pragma unroll
    for (int d = 0; d < 8; d++) o[g][d] = zero;

  char* pb = (char*)&pbuf[wv][0];
  const float scale = 0.08838834764831845f; // 128^-0.5
  const int nt = 2 * blk + 2;               // KV tiles of 64

  auto STAGE = [&](int b, int t) {
    const int s0 = t * 64;
#pragma unroll
    for (int i = 0; i < 4; i++) {          // K: [row s 0..63][col d], 256B rows
      const int c    = i * 256 + tid;
      const int row  = c >> 4;
      const int colb = (c & 15) << 4;
      const int scol = (colb ^ ((row & 7) << 4)) >> 1;
      gload_lds16(Kh + (size_t)(s0 + row) * HEADD + scol,
                  (char*)&Ks[b][0] + (size_t)(i * 256 + wv * 64) * 16);
    }
#pragma unroll
    for (int i = 0; i < 4; i++) {          // V: [row d 0..127][col s], 128B rows
      const int c    = i * 256 + tid;
      const int row  = c >> 3;
      const int colb = (c & 7) << 4;
      const int scol = (colb ^ ((row & 7) << 4)) >> 1;
      gload_lds16(Vh + (size_t)row * T_LEN + s0 + scol,
                  (char*)&Vs[b][0] + (size_t)(i * 256 + wv * 64) * 16);
    }
  };

  int cur = 0;
  STAGE(0, 0);
  __syncthreads();

  for (int t = 0; t < nt; ++t) {
    if (t + 1 < nt) STAGE(cur ^ 1, t + 1);   // prefetch overlaps compute
    const int s0 = t * 64;
    const char* KsB = (const char*)&Ks[cur][0];
    const char* VsB = (const char*)&Vs[cur][0];

    float scv[2][4][4];
#pragma unroll
    for (int sub = 0; sub < 4; sub++) {
      const char* Kbase = KsB + (sub * 16 + fr) * 256;
      f32x4 a0 = zero, a1 = zero;
#pragma unroll
      for (int d0 = 0; d0 < 4; d0++) {
        short8v kf = *(const short8v*)(Kbase + ((d0 * 64 + fkb) ^ swz));
        a0 = __builtin_amdgcn_mfma_f32_16x16x32_bf16(qf[0][d0], kf, a0, 0, 0, 0);
        a1 = __builtin_amdgcn_mfma_f32_16x16x32_bf16(qf[1][d0], kf, a1, 0, 0, 0);
      }
#pragma unroll
      for (int j = 0; j < 4; j++) {
        scv[0][sub][j] = a0[j] * scale;
        scv[1][sub][j] = a1[j] * scale;
      }
    }
    if (t >= nt - 2) {
#pragma unroll
      for (int g = 0; g < 2; g++)
#pragma unroll
        for (int sub = 0; sub < 4; sub++) {
          const int colp = s0 + sub * 16 + fr;
#pragma unroll
          for (int j = 0; j < 4; j++)
            if (colp > qrow0 + g * 16 + rg + j) scv[g][sub][j] = -1e30f;
        }
    }
    float pmax[2][4];
#pragma unroll
    for (int g = 0; g < 2; g++)
#pragma unroll
      for (int j = 0; j < 4; j++)
        pmax[g][j] = fmaxf(fmaxf(scv[g][0][j], scv[g][1][j]),
                           fmaxf(scv[g][2][j], scv[g][3][j]));
    float growth = -1e30f;
#pragma unroll
    for (int g = 0; g < 2; g++)
#pragma unroll
      for (int j = 0; j < 4; j++) growth = fmaxf(growth, pmax[g][j] - mrow[g][j]);
    if (!__all(growth <= 8.0f)) {
#pragma unroll
      for (int g = 0; g < 2; g++)
#pragma unroll
        for (int j = 0; j < 4; j++) {
          float mx = pmax[g][j];
#pragma unroll
          for (int d = 1; d < 16; d <<= 1) mx = fmaxf(mx, __shfl_xor(mx, d));
          const float mn = fmaxf(mrow[g][j], mx);
          const float c  = __expf(mrow[g][j] - mn);
          mrow[g][j] = mn;
          lrow[g][j] *= c;
#pragma unroll
          for (int df = 0; df < 8; df++) o[g][df][j] *= c;
        }
    }
#pragma unroll
    for (int g = 0; g < 2; g++)
#pragma unroll
      for (int j = 0; j < 4; j++) {
        const int prow = g * 16 + rg + j;
        char* prb = pb + prow * 128;
        const int rswz = ((rg + j) & 7) << 4;
        float ps = 0.f;
#pragma unroll
        for (int sub = 0; sub < 4; sub++) {
          const float p = __expf(scv[g][sub][j] - mrow[g][j]);
          ps += p;
          *(short*)(prb + ((((sub * 16 + fr) << 1)) ^ rswz)) = f2bf(p);
        }
        lrow[g][j] += ps;
      }
    asm volatile("" ::: "memory");
    short8v pf[2][2];
#pragma unroll
    for (int g = 0; g < 2; g++)
#pragma unroll
      for (int ks = 0; ks < 2; ks++)
        pf[g][ks] = *(const short8v*)(pb + (g * 16 + fr) * 128 + ((ks * 64 + fkb) ^ swz));
#pragma unroll
    for (int df = 0; df < 8; df++) {
      const char* Vbase = VsB + (df * 16 + fr) * 128;
      short8v vf0 = *(const short8v*)(Vbase + ((0 + fkb) ^ swz));
      short8v vf1 = *(const short8v*)(Vbase + ((64 + fkb) ^ swz));
      o[0][df] = __builtin_amdgcn_mfma_f32_16x16x32_bf16(pf[0][0], vf0, o[0][df], 0, 0, 0);
      o[0][df] = __builtin_amdgcn_mfma_f32_16x16x32_bf16(pf[0][1], vf1, o[0][df], 0, 0, 0);
      o[1][df] = __builtin_amdgcn_mfma_f32_16x16x32_bf16(pf[1][0], vf0, o[1][df], 0, 0, 0);
      o[1][df] = __builtin_amdgcn_mfma_f32_16x16x32_bf16(pf[1][1], vf1, o[1][df], 0, 0, 0);
    }
    __syncthreads();
    cur ^= 1;
  }

#pragma unroll
  for (int g = 0; g < 2; g++)
#pragma unroll
    for (int j = 0; j < 4; j++) {
#pragma unroll
      for (int d = 1; d < 16; d <<= 1) lrow[g][j] += __shfl_xor(lrow[g][j], d);
    }
#pragma unroll
  for (int g = 0; g < 2; g++)
#pragma unroll
    for (int df = 0; df < 8; df++)
#pragma unroll
      for (int j = 0; j < 4; j++) {
        const float v = o[g][df][j] / lrow[g][j];
        attn_out[(size_t)(qrow0 + g * 16 + rg + j) * HDIM + h * HEADD + df * 16 + fr] = f2bf(v);
      }
}

// ---------------- launch ----------------
extern "C" void kernel_launch(void* const* d_in, const int* in_sizes, int n_in,
                              void* d_out, int out_size, void* d_ws, size_t ws_size,
                              hipStream_t stream) {
  (void)out_size; (void)ws_size;
  // size-based input remap (robust to any d_in permutation; sizes are unique)
  int ip = 0, ih = 1, iwq = 2, ib = 3, iwd = 4, il0 = 5, il1 = 6;
  if (n_in == 7) {
    int p = -1, hh = -1, wq = -1, b = -1, wd = -1, l0 = -1, l1 = -1, ok = 1;
    for (int i = 0; i < 7; i++) {
      switch (in_sizes[i]) {
        case 2048:     p  = i; break;
        case 8388608:  hh = i; break;
        case 18874368: wq = i; break;
        case 4608:     b  = i; break;
        case 16777216: wd = i; break;
        case 128:      if (l0 < 0) l0 = i; else l1 = i; break;
        default:       ok = 0; break;
      }
    }
    if (ok && p >= 0 && hh >= 0 && wq >= 0 && b >= 0 && wd >= 0 && l0 >= 0 && l1 >= 0) {
      ip = p; ih = hh; iwq = wq; ib = b; iwd = wd; il0 = l0; il1 = l1;
    }
  }

  const int*   positions = (const int*)d_in[ip];
  const float* hidden    = (const float*)d_in[ih];
  const float* w_qkv     = (const float*)d_in[iwq];
  const float* b_qkv     = (const float*)d_in[ib];
  const float* w_dense   = (const float*)d_in[iwd];
  const float* q_ln      = (const float*)d_in[il0];
  const float* k_ln      = (const float*)d_in[il1];

  char* ws = (char*)d_ws;
  // lifetime-aliased workspace (peak ~73.4 MB):
  short* Ahs   = (short*)(ws + 0);                   // 16.8 MB (dead after gemm1)
  short* Qb    = (short*)(ws + 0);                   // 16.8 MB (aliases Ahs)
  short* Wqkv  = (short*)(ws + (size_t)16777216);    // 37.7 MB (dead after gemm1)
  short* Kb    = (short*)(ws + (size_t)16777216);    // 1.0 MB  (aliases Wqkv)
  short* Vt    = (short*)(ws + (size_t)17825792);    // 1.0 MB  (aliases Wqkv)
  short* Wd    = (short*)(ws + (size_t)18874368);    // 33.5 MB (aliases Wqkv)
  short* qkvb  = (short*)(ws + (size_t)54525952);    // 18.9 MB bf16 (dead after qkv_post)
  short* attnb = (short*)(ws + (size_t)54525952);    // 16.8 MB (aliases qkvb)

  cast_pair<<<dim3(3072), dim3(256), 0, stream>>>(
      hidden, Ahs, (T_LEN * HDIM) / 4, w_qkv, Wqkv, (QKVN * HDIM) / 4);
  gemm_bt<1><<<dim3(QKVN / 128, T_LEN / 128), dim3(256), 0, stream>>>(
      Ahs, Wqkv, b_qkv, (void*)qkvb, T_LEN, QKVN, HDIM);
  qkv_post_kernel<<<dim3(T_LEN, 9), dim3(256), 0, stream>>>(
      qkvb, positions, q_ln, k_ln, Qb, Kb, Vt);
  cast_f32_to_bf16<<<dim3(2048), dim3(256), 0, stream>>>(w_dense, Wd, (HDIM * HDIM) / 4);
  attn_kernel<<<dim3(16, NHEADS), dim3(256), 0, stream>>>(Qb, Kb, Vt, attnb);
  gemm_bt<0><<<dim3(HDIM / 128, T_LEN / 128), dim3(256), 0, stream>>>(
      attnb, Wd, nullptr, d_out, T_LEN, HDIM, HDIM);
}

// Round 22
// 307.985 us; speedup vs baseline: 1.1440x; 1.0266x over previous
//
#include <hip/hip_runtime.h>
#include <cstdint>
#include <cstddef>

// ---------------- types ----------------
typedef short short4v __attribute__((ext_vector_type(4)));
typedef short short8v __attribute__((ext_vector_type(8)));
typedef float f32x4   __attribute__((ext_vector_type(4)));

#define T_LEN  2048
#define HDIM   4096
#define NHEADS 32
#define HEADD  128
#define QKVN   4608   // (32 + 2*2) * 128

static __device__ __forceinline__ short f2bf(float f) {
  __bf16 h = (__bf16)f;               // RNE fptrunc
  return __builtin_bit_cast(short, h);
}
static __device__ __forceinline__ float bf2f(short u) {
  return __builtin_bit_cast(float, ((unsigned int)(unsigned short)u) << 16);  // exact
}

static __device__ __forceinline__ void gload_lds16(const void* g, void* l) {
  // async global->LDS, 16B per lane; LDS dest is wave-uniform base + lane*16
  __builtin_amdgcn_global_load_lds((const __attribute__((address_space(1))) void*)g,
                                   (__attribute__((address_space(3))) void*)l,
                                   16, 0, 0);
}

// ---------------- casts ----------------
__global__ void cast_pair(const float* __restrict__ a, short* __restrict__ oa, int na4,
                          const float* __restrict__ b, short* __restrict__ ob, int nb4) {
  int idx = blockIdx.x * blockDim.x + threadIdx.x;
  int stride = gridDim.x * blockDim.x;
  const int ntot = na4 + nb4;
  for (int i = idx; i < ntot; i += stride) {
    const float4* src = (i < na4) ? ((const float4*)a + i) : ((const float4*)b + (i - na4));
    short4v* dst      = (i < na4) ? ((short4v*)oa + i)     : ((short4v*)ob + (i - na4));
    float4 v = *src;
    short4v o;
    o[0] = f2bf(v.x); o[1] = f2bf(v.y); o[2] = f2bf(v.z); o[3] = f2bf(v.w);
    *dst = o;
  }
}

__global__ void cast_f32_to_bf16(const float* __restrict__ in, short* __restrict__ out, int n4) {
  int idx = blockIdx.x * blockDim.x + threadIdx.x;
  int stride = gridDim.x * blockDim.x;
  const float4* in4 = (const float4*)in;
  short4v* out4 = (short4v*)out;
  for (int i = idx; i < n4; i += stride) {
    float4 v = in4[i];
    short4v o;
    o[0] = f2bf(v.x); o[1] = f2bf(v.y); o[2] = f2bf(v.z); o[3] = f2bf(v.w);
    out4[i] = o;
  }
}

// ---------------- GEMM  C[M][N] = A[M][K] * B[N][K]^T (+bias) ---------------
// R19/R21-measured (97us): BK=64 single-buffer (32KB, 2 blocks/CU), rule-#21
// XOR swizzle (conflicts 0), T1 bijective XCD swizzle (FETCH ~90MB).
template <int OUT_BF16>
__global__ __launch_bounds__(256, 2) void gemm_bt(
    const short* __restrict__ A,     // [M][K] bf16
    const short* __restrict__ B,     // [N][K] bf16
    const float* __restrict__ bias,  // [N] f32 or nullptr
    void* __restrict__ Cout,         // [M][N] f32 or bf16
    int M, int N, int K)
{
  __shared__ short sA[128 * 64];   // [row][k] 128B rows, swizzled, 16KB
  __shared__ short sB[128 * 64];
  const int tid  = threadIdx.x;
  const int lane = tid & 63;
  const int wv   = tid >> 6;
  const int wr   = wv >> 1;
  const int wc   = wv & 1;

  const int nwg  = gridDim.x * gridDim.y;
  int wgid = blockIdx.y * gridDim.x + blockIdx.x;
  wgid = (wgid & 7) * (nwg >> 3) + (wgid >> 3);
  const int bn0 = (wgid / gridDim.y) * 128;
  const int bm0 = (wgid % gridDim.y) * 128;

  const int fr  = lane & 15;
  const int fkb = (lane >> 4) << 4;
  const int swz = (fr & 7) << 4;

  const int c_row  = tid >> 3;
  const int c_colb = (tid & 7) << 4;
  const int c_scol = (c_colb ^ ((c_row & 7) << 4)) >> 1;

  auto STAGE = [&](int kt) {
#pragma unroll
    for (int i = 0; i < 4; i++) {
      const int row = i * 32 + c_row;
      gload_lds16(A + (size_t)(bm0 + row) * K + kt + c_scol,
                  (char*)sA + (size_t)(i * 256 + wv * 64) * 16);
      gload_lds16(B + (size_t)(bn0 + row) * K + kt + c_scol,
                  (char*)sB + (size_t)(i * 256 + wv * 64) * 16);
    }
  };

  f32x4 zero = {0.f, 0.f, 0.f, 0.f};
  f32x4 acc[4][4];
#pragma unroll
  for (int m = 0; m < 4; m++)
#pragma unroll
    for (int n = 0; n < 4; n++) acc[m][n] = zero;

  for (int kt = 0; kt < K; kt += 64) {
    STAGE(kt);
    __syncthreads();
    const char* aB = (const char*)sA;
    const char* bB = (const char*)sB;
#pragma unroll
    for (int ks = 0; ks < 2; ks++) {
      short8v af[4], bfr[4];
#pragma unroll
      for (int m = 0; m < 4; m++) {
        const int row = wr * 64 + m * 16 + fr;
        af[m] = *(const short8v*)(aB + row * 128 + ((ks * 64 + fkb) ^ swz));
      }
#pragma unroll
      for (int n = 0; n < 4; n++) {
        const int row = wc * 64 + n * 16 + fr;
        bfr[n] = *(const short8v*)(bB + row * 128 + ((ks * 64 + fkb) ^ swz));
      }
#pragma unroll
      for (int m = 0; m < 4; m++)
#pragma unroll
        for (int n = 0; n < 4; n++)
          acc[m][n] = __builtin_amdgcn_mfma_f32_16x16x32_bf16(af[m], bfr[n], acc[m][n], 0, 0, 0);
    }
    __syncthreads();
  }

  const int rg = (lane >> 4) * 4;
#pragma unroll
  for (int m = 0; m < 4; m++) {
#pragma unroll
    for (int n = 0; n < 4; n++) {
      const int gcol = bn0 + wc * 64 + n * 16 + fr;
      const float bv = bias ? bias[gcol] : 0.0f;
#pragma unroll
      for (int j = 0; j < 4; j++) {
        const int grow = bm0 + wr * 64 + m * 16 + rg + j;
        const float v = acc[m][n][j] + bv;
        if (OUT_BF16)
          ((short*)Cout)[(size_t)grow * N + gcol] = f2bf(v);
        else
          ((float*)Cout)[(size_t)grow * N + gcol] = v;
      }
    }
  }
}

// ---------------- per-head RMSNorm + RoPE, 4 heads per 256-thread block -----
__global__ __launch_bounds__(256) void qkv_post_kernel(
    const short* __restrict__ qkvb,      // [T][4608] bf16 (bias included)
    const int*   __restrict__ positions,
    const float* __restrict__ q_ln,      // [128] f32
    const float* __restrict__ k_ln,      // [128] f32
    short* __restrict__ Qb,   // [NH][T][HD]
    short* __restrict__ Kb,   // [NKV][T][HD]
    short* __restrict__ Vt)   // [NKV][HD][T]
{
  const int t = blockIdx.x;
  const int h = blockIdx.y * 4 + (threadIdx.x >> 6);
  const int lane = threadIdx.x & 63;
  const unsigned int pk =
      ((const unsigned int*)(qkvb + (size_t)t * QKVN + h * HEADD))[lane];
  float x = bf2f((short)(pk & 0xffffu));
  float y = bf2f((short)(pk >> 16));

  if (h >= 34) { // V: transpose only
    const int hv = h - 34;
    short* dst = Vt + ((size_t)hv * HEADD + 2 * lane) * T_LEN + t;
    dst[0]     = f2bf(x);
    dst[T_LEN] = f2bf(y);
    return;
  }

  float ss = x * x + y * y;
#pragma unroll
  for (int d = 32; d > 0; d >>= 1) ss += __shfl_xor(ss, d);
  const float r = rsqrtf(ss * (1.0f / 128.0f) + 1e-5f);
  const float* lnw = (h < 32) ? q_ln : k_ln;
  x = x * r * lnw[2 * lane];
  y = y * r * lnw[2 * lane + 1];

  if (lane < 32) { // rotary pairs (2i,2i+1), i<32: ang = pos * 10000^(-i/32)
    const float pos = (float)positions[t];
    const float ang = pos * powf(10000.0f, -(float)lane * (1.0f / 32.0f));
    const float c = cosf(ang), s = sinf(ang);
    const float r1 = x * c - y * s;
    const float r2 = y * c + x * s;
    x = r1; y = r2;
  }

  short* dst = (h < 32) ? (Qb + ((size_t)h * T_LEN + t) * HEADD + 2 * lane)
                        : (Kb + ((size_t)(h - 32) * T_LEN + t) * HEADD + 2 * lane);
  dst[0] = f2bf(x);
  dst[1] = f2bf(y);
}

// ---------------- causal flash attention, GQA 16:1, PAIR-BALANCED ----------
// Block x handles q-tile pair (x, 31-x), 64 rows each: per-wave group 0 =
// 16 rows of tile x, group 1 = 16 rows of tile 31-x. Per-block MFMA work =
// (x+1)+(32-x) = 33 tile-units, CONSTANT -> fixes the measured 16x per-CU
// imbalance (attn MfmaUtil 15%). K/V staged over group-1's range (nt=32-x,
// dbuf prefetch); group-0 compute skipped via wave-uniform `dual = t<=x`.
__global__ __launch_bounds__(256, 2) void attn_kernel(
    const short* __restrict__ Qb,   // [NH][T][HD]
    const short* __restrict__ Kb,   // [NKV][T][HD]
    const short* __restrict__ Vt,   // [NKV][HD][T]
    short* __restrict__ attn_out)   // [T][NH*HD] bf16
{
  __shared__ short Ks[2][64 * 128];   // [s][d] swizzled, 2x16KB
  __shared__ short Vs[2][128 * 64];   // [d][s] swizzled, 2x16KB
  __shared__ short pbuf[4][32 * 64];  // per-wave P tile [row][col] swizzled, 16KB
  const int x    = blockIdx.x;        // pair index 0..15
  const int h    = blockIdx.y;
  const int hkv  = h >> 4;
  const int tid  = threadIdx.x;
  const int lane = tid & 63;
  const int wv   = tid >> 6;
  const int qA   = x * 64 + wv * 16;          // group 0 rows (tile x)
  const int qB   = (31 - x) * 64 + wv * 16;   // group 1 rows (tile 31-x)
  const int nt   = 32 - x;                    // KV tiles of 64 (group-1 range)
  const int fr = lane & 15;
  const int fk = (lane >> 4) * 8;     // shorts
  const int fkb = (lane >> 4) << 4;   // bytes
  const int rg = (lane >> 4) * 4;
  const int swz = (fr & 7) << 4;

  const short* Kh = Kb + (size_t)hkv * T_LEN * HEADD;
  const short* Vh = Vt + (size_t)hkv * HEADD * T_LEN;

  short8v qf0[4], qf1[4];
  {
    const short* QrowA = Qb + ((size_t)h * T_LEN + qA + fr) * HEADD + fk;
    const short* QrowB = Qb + ((size_t)h * T_LEN + qB + fr) * HEADD + fk;
#pragma unroll
    for (int d0 = 0; d0 < 4; d0++) {
      qf0[d0] = *(const short8v*)(QrowA + d0 * 32);
      qf1[d0] = *(const short8v*)(QrowB + d0 * 32);
    }
  }

  float mrow[2][4], lrow[2][4];
#pragma unroll
  for (int g = 0; g < 2; g++)
#pragma unroll
    for (int j = 0; j < 4; j++) { mrow[g][j] = -1e30f; lrow[g][j] = 0.f; }
  f32x4 zero = {0.f, 0.f, 0.f, 0.f};
  f32x4 o[2][8];
#pragma unroll
  for (int g = 0; g < 2; g++)
#pragma unroll
    for (int d = 0; d < 8; d++) o[g][d] = zero;

  char* pb = (char*)&pbuf[wv][0];
  const float scale = 0.08838834764831845f; // 128^-0.5

  auto STAGE = [&](int b, int t) {
    const int s0 = t * 64;
#pragma unroll
    for (int i = 0; i < 4; i++) {          // K: [row s 0..63][col d], 256B rows
      const int c    = i * 256 + tid;
      const int row  = c >> 4;
      const int colb = (c & 15) << 4;
      const int scol = (colb ^ ((row & 7) << 4)) >> 1;
      gload_lds16(Kh + (size_t)(s0 + row) * HEADD + scol,
                  (char*)&Ks[b][0] + (size_t)(i * 256 + wv * 64) * 16);
    }
#pragma unroll
    for (int i = 0; i < 4; i++) {          // V: [row d 0..127][col s], 128B rows
      const int c    = i * 256 + tid;
      const int row  = c >> 3;
      const int colb = (c & 7) << 4;
      const int scol = (colb ^ ((row & 7) << 4)) >> 1;
      gload_lds16(Vh + (size_t)row * T_LEN + s0 + scol,
                  (char*)&Vs[b][0] + (size_t)(i * 256 + wv * 64) * 16);
    }
  };

  int cur = 0;
  STAGE(0, 0);
  __syncthreads();

  for (int t = 0; t < nt; ++t) {
    if (t + 1 < nt) STAGE(cur ^ 1, t + 1);   // prefetch overlaps compute
    const int s0 = t * 64;
    const bool dual = (t <= x);              // group 0 active? (wave-uniform)
    const char* KsB = (const char*)&Ks[cur][0];
    const char* VsB = (const char*)&Vs[cur][0];

    // ---- scores: group 1 always, group 0 when dual (shared kf reads)
    float scv0[4][4], scv1[4][4];
#pragma unroll
    for (int sub = 0; sub < 4; sub++) {
      const char* Kbase = KsB + (sub * 16 + fr) * 256;
      f32x4 a0 = zero, a1 = zero;
#pragma unroll
      for (int d0 = 0; d0 < 4; d0++) {
        short8v kf = *(const short8v*)(Kbase + ((d0 * 64 + fkb) ^ swz));
        a1 = __builtin_amdgcn_mfma_f32_16x16x32_bf16(qf1[d0], kf, a1, 0, 0, 0);
        if (dual) a0 = __builtin_amdgcn_mfma_f32_16x16x32_bf16(qf0[d0], kf, a0, 0, 0, 0);
      }
#pragma unroll
      for (int j = 0; j < 4; j++) {
        scv1[sub][j] = a1[j] * scale;
        scv0[sub][j] = a0[j] * scale;
      }
    }
    // ---- causal masks (each group only at its own diagonal tile)
    if (t == x) {
#pragma unroll
      for (int sub = 0; sub < 4; sub++) {
        const int colp = s0 + sub * 16 + fr;
#pragma unroll
        for (int j = 0; j < 4; j++)
          if (colp > qA + rg + j) scv0[sub][j] = -1e30f;
      }
    }
    if (t == nt - 1) {
#pragma unroll
      for (int sub = 0; sub < 4; sub++) {
        const int colp = s0 + sub * 16 + fr;
#pragma unroll
        for (int j = 0; j < 4; j++)
          if (colp > qB + rg + j) scv1[sub][j] = -1e30f;
      }
    }
    // ---- defer-max gate (T13, THR=8) over participating groups
    float pmax1[4], pmax0[4];
#pragma unroll
    for (int j = 0; j < 4; j++)
      pmax1[j] = fmaxf(fmaxf(scv1[0][j], scv1[1][j]), fmaxf(scv1[2][j], scv1[3][j]));
    float growth = -1e30f;
#pragma unroll
    for (int j = 0; j < 4; j++) growth = fmaxf(growth, pmax1[j] - mrow[1][j]);
    if (dual) {
#pragma unroll
      for (int j = 0; j < 4; j++) {
        pmax0[j] = fmaxf(fmaxf(scv0[0][j], scv0[1][j]), fmaxf(scv0[2][j], scv0[3][j]));
        growth = fmaxf(growth, pmax0[j] - mrow[0][j]);
      }
    }
    if (!__all(growth <= 8.0f)) {
#pragma unroll
      for (int j = 0; j < 4; j++) {
        float mx = pmax1[j];
#pragma unroll
        for (int d = 1; d < 16; d <<= 1) mx = fmaxf(mx, __shfl_xor(mx, d));
        const float mn = fmaxf(mrow[1][j], mx);
        const float c  = __expf(mrow[1][j] - mn);
        mrow[1][j] = mn;
        lrow[1][j] *= c;
#pragma unroll
        for (int df = 0; df < 8; df++) o[1][df][j] *= c;
      }
      if (dual) {
#pragma unroll
        for (int j = 0; j < 4; j++) {
          float mx = pmax0[j];
#pragma unroll
          for (int d = 1; d < 16; d <<= 1) mx = fmaxf(mx, __shfl_xor(mx, d));
          const float mn = fmaxf(mrow[0][j], mx);
          const float c  = __expf(mrow[0][j] - mn);
          mrow[0][j] = mn;
          lrow[0][j] *= c;
#pragma unroll
          for (int df = 0; df < 8; df++) o[0][df][j] *= c;
        }
      }
    }
    // ---- exp + per-lane l + P -> swizzled LDS (pbuf rows: g0 0-15, g1 16-31)
#pragma unroll
    for (int j = 0; j < 4; j++) {
      const int rswz = ((rg + j) & 7) << 4;
      char* prb1 = pb + (16 + rg + j) * 128;
      float ps1 = 0.f;
#pragma unroll
      for (int sub = 0; sub < 4; sub++) {
        const float p = __expf(scv1[sub][j] - mrow[1][j]);
        ps1 += p;
        *(short*)(prb1 + ((((sub * 16 + fr) << 1)) ^ rswz)) = f2bf(p);
      }
      lrow[1][j] += ps1;
    }
    if (dual) {
#pragma unroll
      for (int j = 0; j < 4; j++) {
        const int rswz = ((rg + j) & 7) << 4;
        char* prb0 = pb + (rg + j) * 128;
        float ps0 = 0.f;
#pragma unroll
        for (int sub = 0; sub < 4; sub++) {
          const float p = __expf(scv0[sub][j] - mrow[0][j]);
          ps0 += p;
          *(short*)(prb0 + ((((sub * 16 + fr) << 1)) ^ rswz)) = f2bf(p);
        }
        lrow[0][j] += ps0;
      }
    }
    asm volatile("" ::: "memory");
    // ---- PV: shared vf reads; group 1 always, group 0 when dual
    short8v pf1[2], pf0[2];
#pragma unroll
    for (int ks = 0; ks < 2; ks++) {
      pf1[ks] = *(const short8v*)(pb + (16 + fr) * 128 + ((ks * 64 + fkb) ^ swz));
      pf0[ks] = *(const short8v*)(pb + fr * 128 + ((ks * 64 + fkb) ^ swz));
    }
#pragma unroll
    for (int df = 0; df < 8; df++) {
      const char* Vbase = VsB + (df * 16 + fr) * 128;
      short8v vf0 = *(const short8v*)(Vbase + ((0 + fkb) ^ swz));
      short8v vf1 = *(const short8v*)(Vbase + ((64 + fkb) ^ swz));
      o[1][df] = __builtin_amdgcn_mfma_f32_16x16x32_bf16(pf1[0], vf0, o[1][df], 0, 0, 0);
      o[1][df] = __builtin_amdgcn_mfma_f32_16x16x32_bf16(pf1[1], vf1, o[1][df], 0, 0, 0);
      if (dual) {
        o[0][df] = __builtin_amdgcn_mfma_f32_16x16x32_bf16(pf0[0], vf0, o[0][df], 0, 0, 0);
        o[0][df] = __builtin_amdgcn_mfma_f32_16x16x32_bf16(pf0[1], vf1, o[0][df], 0, 0, 0);
      }
    }
    __syncthreads();
    cur ^= 1;
  }

  // ---- final denominator reduce + output (group 0 -> tile x, group 1 -> 31-x)
#pragma unroll
  for (int g = 0; g < 2; g++)
#pragma unroll
    for (int j = 0; j < 4; j++) {
#pragma unroll
      for (int d = 1; d < 16; d <<= 1) lrow[g][j] += __shfl_xor(lrow[g][j], d);
    }
#pragma unroll
  for (int df = 0; df < 8; df++)
#pragma unroll
    for (int j = 0; j < 4; j++) {
      const float v0 = o[0][df][j] / lrow[0][j];
      attn_out[(size_t)(qA + rg + j) * HDIM + h * HEADD + df * 16 + fr] = f2bf(v0);
      const float v1 = o[1][df][j] / lrow[1][j];
      attn_out[(size_t)(qB + rg + j) * HDIM + h * HEADD + df * 16 + fr] = f2bf(v1);
    }
}

// ---------------- launch ----------------
extern "C" void kernel_launch(void* const* d_in, const int* in_sizes, int n_in,
                              void* d_out, int out_size, void* d_ws, size_t ws_size,
                              hipStream_t stream) {
  (void)out_size; (void)ws_size;
  // size-based input remap (robust to any d_in permutation; sizes are unique)
  int ip = 0, ih = 1, iwq = 2, ib = 3, iwd = 4, il0 = 5, il1 = 6;
  if (n_in == 7) {
    int p = -1, hh = -1, wq = -1, b = -1, wd = -1, l0 = -1, l1 = -1, ok = 1;
    for (int i = 0; i < 7; i++) {
      switch (in_sizes[i]) {
        case 2048:     p  = i; break;
        case 8388608:  hh = i; break;
        case 18874368: wq = i; break;
        case 4608:     b  = i; break;
        case 16777216: wd = i; break;
        case 128:      if (l0 < 0) l0 = i; else l1 = i; break;
        default:       ok = 0; break;
      }
    }
    if (ok && p >= 0 && hh >= 0 && wq >= 0 && b >= 0 && wd >= 0 && l0 >= 0 && l1 >= 0) {
      ip = p; ih = hh; iwq = wq; ib = b; iwd = wd; il0 = l0; il1 = l1;
    }
  }

  const int*   positions = (const int*)d_in[ip];
  const float* hidden    = (const float*)d_in[ih];
  const float* w_qkv     = (const float*)d_in[iwq];
  const float* b_qkv     = (const float*)d_in[ib];
  const float* w_dense   = (const float*)d_in[iwd];
  const float* q_ln      = (const float*)d_in[il0];
  const float* k_ln      = (const float*)d_in[il1];

  char* ws = (char*)d_ws;
  // lifetime-aliased workspace (peak ~73.4 MB):
  short* Ahs   = (short*)(ws + 0);                   // 16.8 MB (dead after gemm1)
  short* Qb    = (short*)(ws + 0);                   // 16.8 MB (aliases Ahs)
  short* Wqkv  = (short*)(ws + (size_t)16777216);    // 37.7 MB (dead after gemm1)
  short* Kb    = (short*)(ws + (size_t)16777216);    // 1.0 MB  (aliases Wqkv)
  short* Vt    = (short*)(ws + (size_t)17825792);    // 1.0 MB  (aliases Wqkv)
  short* Wd    = (short*)(ws + (size_t)18874368);    // 33.5 MB (aliases Wqkv)
  short* qkvb  = (short*)(ws + (size_t)54525952);    // 18.9 MB bf16 (dead after qkv_post)
  short* attnb = (short*)(ws + (size_t)54525952);    // 16.8 MB (aliases qkvb)

  cast_pair<<<dim3(3072), dim3(256), 0, stream>>>(
      hidden, Ahs, (T_LEN * HDIM) / 4, w_qkv, Wqkv, (QKVN * HDIM) / 4);
  gemm_bt<1><<<dim3(QKVN / 128, T_LEN / 128), dim3(256), 0, stream>>>(
      Ahs, Wqkv, b_qkv, (void*)qkvb, T_LEN, QKVN, HDIM);
  qkv_post_kernel<<<dim3(T_LEN, 9), dim3(256), 0, stream>>>(
      qkvb, positions, q_ln, k_ln, Qb, Kb, Vt);
  cast_f32_to_bf16<<<dim3(2048), dim3(256), 0, stream>>>(w_dense, Wd, (HDIM * HDIM) / 4);
  attn_kernel<<<dim3(16, NHEADS), dim3(256), 0, stream>>>(Qb, Kb, Vt, attnb);
  gemm_bt<0><<<dim3(HDIM / 128, T_LEN / 128), dim3(256), 0, stream>>>(
      attnb, Wd, nullptr, d_out, T_LEN, HDIM, HDIM);
}